// Round 11
// baseline (70.739 us; speedup 1.0000x reference)
//
#include <hip/hip_runtime.h>
#include <stdint.h>

// Problem dims (fixed by reference setup_inputs)
#define NNODES 20000
#define NSRC   2048
#define DIN    128
#define BM     32          // rows per block (2 waves x 16); grid 625 exact

typedef short s16x8 __attribute__((ext_vector_type(8)));
typedef unsigned short u16x8 __attribute__((ext_vector_type(8)));
typedef float f32x4 __attribute__((ext_vector_type(4)));

// round-to-nearest-even f32 -> bf16 bits
static __device__ __forceinline__ unsigned short f2bf(float f) {
  union { float f; unsigned int u; } v; v.f = f;
  unsigned int r = v.u + 0x7FFFu + ((v.u >> 16) & 1u);
  return (unsigned short)(r >> 16);
}

static __device__ __forceinline__ s16x8 pack8(float4 a, float4 b) {
  s16x8 r;
  r[0] = (short)f2bf(a.x); r[1] = (short)f2bf(a.y);
  r[2] = (short)f2bf(a.z); r[3] = (short)f2bf(a.w);
  r[4] = (short)f2bf(b.x); r[5] = (short)f2bf(b.y);
  r[6] = (short)f2bf(b.z); r[7] = (short)f2bf(b.w);
  return r;
}

static __device__ __forceinline__ s16x8 load_cvt8(const float* __restrict__ p) {
  return pack8(*reinterpret_cast<const float4*>(p),
               *reinterpret_cast<const float4*>(p + 4));
}

#define GLL16(g, l)                                                          \
  __builtin_amdgcn_global_load_lds(                                          \
      (const __attribute__((address_space(1))) void*)(g),                    \
      (__attribute__((address_space(3))) void*)(l), 16, 0, 0)

// ---------------------------------------------------------------------------
// Kernel 1: support = x[src_idx] @ W, written DIRECTLY in MFMA-fragment-linear
// order: supTp[((kk*8 + n)*64 + lane)*8 + e] = bf16(support[kk*32 + (lane>>4)*8
// + e][n*16 + (lane&15)]).  (validated R7-R9)
// ---------------------------------------------------------------------------
__global__ __launch_bounds__(128) void support_kernel(
    const float* __restrict__ x, const float* __restrict__ W,
    const int* __restrict__ src_idx, unsigned short* __restrict__ supTp) {
  __shared__ float xrows[8][DIN];
  const int j = threadIdx.x;           // output feature 0..127
  const int s0 = blockIdx.x * 8;       // first source (k-index) of this block
#pragma unroll
  for (int i = 0; i < 8; ++i) {
    const int src = src_idx[s0 + i];
    xrows[i][j] = x[(size_t)src * DIN + j];
  }
  __syncthreads();
  float acc[8];
#pragma unroll
  for (int i = 0; i < 8; ++i) acc[i] = 0.f;
  for (int k = 0; k < DIN; ++k) {
    const float w = W[(size_t)k * DIN + j];   // coalesced across threads
#pragma unroll
    for (int i = 0; i < 8; ++i) acc[i] += xrows[i][k] * w;  // LDS broadcast
  }
  u16x8 o;
#pragma unroll
  for (int i = 0; i < 8; ++i) o[i] = f2bf(acc[i]);
  const int kk = s0 >> 5;              // 32-wide k-chunk
  const int g2 = (s0 >> 3) & 3;        // k-slot group within chunk
  const int n = j >> 4;                // n-tile
  const int lane = (j & 15) + g2 * 16; // MFMA lane holding these 8 elements
  *reinterpret_cast<u16x8*>(&supTp[(size_t)((kk * 8 + n) * 64 + lane) * 8]) = o;
}

// ---------------------------------------------------------------------------
// Kernel 2: out = LeakyReLU(A @ support) @ dense0_w^T
// R11: ZERO barriers. Waves fully self-paced (phase-skew = mutual latency
// hiding). Block = 128 thr / 2 waves, wave owns 16 rows; grid 625.
//  - B: DIRECT register loads from fragment-packed supTp — each B-frag is one
//    coalesced 1KB instruction (16B/lane x 64 lanes contiguous); L1-resident
//    (16KB/chunk), shared by co-resident waves. No LDS, no barrier.
//  - A: wave-PRIVATE gll double-buffer (8KB/wave), counted vmcnt(4)
//    (A-lookahead 2 chunks); lgkmcnt(0)+sched_barrier before refill of the
//    just-read buffer (rule #18). Source XOR-slot-swizzle as validated R7-R9.
// MFMA 16x16x32 bf16 layouts (validated R2-R10):
//   A-frag: lane l holds A[l&15][(l>>4)*8+e]; B-frag: B[(l>>4)*8+e][l&15]
//   C/D:    lane l holds C[(l>>4)*4+r][l&15]
// ---------------------------------------------------------------------------
__global__ __launch_bounds__(128) void fused_gcn_kernel(
    const float* __restrict__ A,             // [NNODES][NSRC] f32
    const unsigned short* __restrict__ supTp,// fragment-packed, 512 KB
    const float* __restrict__ Wd,            // dense0_w [DIN][DIN] f32
    float* __restrict__ out) {               // [NNODES][DIN] f32
  const int tid = threadIdx.x;
  const int lane = tid & 63;
  const int w = tid >> 6;                    // wave 0..1
  const int r16 = lane & 15;
  const int g = lane >> 4;
  const int rowBase = blockIdx.x * BM;

  __shared__ float Ap[2][2][16 * 64];        // [wave][buf][16 rows x 64] 16KB
  __shared__ unsigned short act[2][16 * 136];// per-wave act tile, 8.5KB

  f32x4 acc[8];
#pragma unroll
  for (int n = 0; n < 8; ++n) acc[n] = (f32x4){0.f, 0.f, 0.f, 0.f};

  // wave-private A staging: instr i2 covers local rows 4*i2..+3 (4 x 256B
  // segments). Source slot pre-swizzled: slot_src = (lane&15) ^ (rl&7).
#define ISSUE_A(buf, c)                                                       \
  {                                                                           \
    _Pragma("unroll") for (int i2 = 0; i2 < 4; ++i2) {                        \
      const int rl = i2 * 4 + (lane >> 4);                                    \
      GLL16(A + (size_t)(rowBase + w * 16 + rl) * NSRC + (c) * 64 +           \
                (((lane & 15) ^ (rl & 7)) << 2),                              \
            &Ap[w][buf][i2 * 256]);                                           \
    }                                                                         \
  }

  ISSUE_A(0, 0);
  ISSUE_A(1, 1);

  for (int c = 0; c < 32; ++c) {
    if (c < 31) {
      asm volatile("s_waitcnt vmcnt(4)" ::: "memory");  // A(c) landed; A(c+1) in flight
    } else {
      asm volatile("s_waitcnt vmcnt(0)" ::: "memory");
    }
    // B fragments for chunk c: direct coalesced 1KB loads (L1/L2-hot)
    const unsigned short* bsrc = supTp + (size_t)c * 8192;
    s16x8 b0[8], b1[8];
#pragma unroll
    for (int n = 0; n < 8; ++n)
      b0[n] = *reinterpret_cast<const s16x8*>(&bsrc[(size_t)(n * 64 + lane) * 8]);
#pragma unroll
    for (int n = 0; n < 8; ++n)
      b1[n] = *reinterpret_cast<const s16x8*>(
          &bsrc[(size_t)((8 + n) * 64 + lane) * 8]);
    // A fragments from wave-private LDS (swizzled read)
    const float* rb = &Ap[w][c & 1][r16 * 64];
    s16x8 afr[2];
#pragma unroll
    for (int kk2 = 0; kk2 < 2; ++kk2) {
      const int t0 = kk2 * 8 + g * 2;
      const float4 lo =
          *reinterpret_cast<const float4*>(&rb[((t0) ^ (r16 & 7)) << 2]);
      const float4 hi =
          *reinterpret_cast<const float4*>(&rb[((t0 + 1) ^ (r16 & 7)) << 2]);
      afr[kk2] = pack8(lo, hi);
    }
    // buffer reads complete before refill issue (rule #18 fence pair)
    asm volatile("s_waitcnt lgkmcnt(0)" ::: "memory");
    __builtin_amdgcn_sched_barrier(0);
    if (c < 30) ISSUE_A(c & 1, c + 2);
#pragma unroll
    for (int n = 0; n < 8; ++n)
      acc[n] = __builtin_amdgcn_mfma_f32_16x16x32_bf16(afr[0], b0[n], acc[n], 0, 0, 0);
#pragma unroll
    for (int n = 0; n < 8; ++n)
      acc[n] = __builtin_amdgcn_mfma_f32_16x16x32_bf16(afr[1], b1[n], acc[n], 0, 0, 0);
  }

  // ---- epilogue: LeakyReLU -> per-wave act tile -> GEMM2 -> store ---------
  unsigned short* actw = act[w];             // [16][136]
#pragma unroll
  for (int n = 0; n < 8; ++n)
#pragma unroll
    for (int r = 0; r < 4; ++r) {
      float v = acc[n][r];
      v = (v >= 0.f) ? v : 0.01f * v;
      actw[(g * 4 + r) * 136 + n * 16 + r16] = f2bf(v);
    }
  // own-wave write->read; compiler orders via lgkmcnt

  f32x4 acc2[8];
#pragma unroll
  for (int n = 0; n < 8; ++n) acc2[n] = (f32x4){0.f, 0.f, 0.f, 0.f};
#pragma unroll
  for (int k2 = 0; k2 < 4; ++k2) {
    const int k = k2 * 32 + g * 8;
    const s16x8 a2 = *reinterpret_cast<const s16x8*>(&actw[r16 * 136 + k]);
#pragma unroll
    for (int n = 0; n < 8; ++n) {
      const s16x8 b2 = load_cvt8(Wd + (size_t)(n * 16 + r16) * DIN + k);
      acc2[n] =
          __builtin_amdgcn_mfma_f32_16x16x32_bf16(a2, b2, acc2[n], 0, 0, 0);
    }
  }
#pragma unroll
  for (int n = 0; n < 8; ++n)
#pragma unroll
    for (int r = 0; r < 4; ++r)
      out[(size_t)(rowBase + w * 16 + g * 4 + r) * DIN + n * 16 + r16] =
          acc2[n][r];
}

// ---------------------------------------------------------------------------
extern "C" void kernel_launch(void* const* d_in, const int* in_sizes, int n_in,
                              void* d_out, int out_size, void* d_ws, size_t ws_size,
                              hipStream_t stream) {
  const float* x   = (const float*)d_in[0];   // [20000][128]
  const float* A   = (const float*)d_in[1];   // [20000][2048]
  const float* W   = (const float*)d_in[2];   // [128][128]
  const float* Wd  = (const float*)d_in[3];   // [128][128]
  const int*   src = (const int*)d_in[4];     // [2048]
  float* out = (float*)d_out;

  unsigned short* supTp = (unsigned short*)d_ws;  // 512 KB, fragment-packed

  support_kernel<<<NSRC / 8, 128, 0, stream>>>(x, W, src, supTp);
  fused_gcn_kernel<<<NNODES / BM, 128, 0, stream>>>(A, supTp, Wd, out);
}

// Round 13
// 60.684 us; speedup vs baseline: 1.1657x; 1.1657x over previous
//
#include <hip/hip_runtime.h>
#include <stdint.h>

// Problem dims (fixed by reference setup_inputs)
#define NNODES 20000
#define NSRC   2048
#define DIN    128

typedef short s16x8 __attribute__((ext_vector_type(8)));
typedef unsigned short u16x8 __attribute__((ext_vector_type(8)));
typedef float f32x4 __attribute__((ext_vector_type(4)));

// round-to-nearest-even f32 -> bf16 bits
static __device__ __forceinline__ unsigned short f2bf(float f) {
  union { float f; unsigned int u; } v; v.f = f;
  unsigned int r = v.u + 0x7FFFu + ((v.u >> 16) & 1u);
  return (unsigned short)(r >> 16);
}

static __device__ __forceinline__ s16x8 pack8(float4 a, float4 b) {
  s16x8 r;
  r[0] = (short)f2bf(a.x); r[1] = (short)f2bf(a.y);
  r[2] = (short)f2bf(a.z); r[3] = (short)f2bf(a.w);
  r[4] = (short)f2bf(b.x); r[5] = (short)f2bf(b.y);
  r[6] = (short)f2bf(b.z); r[7] = (short)f2bf(b.w);
  return r;
}

static __device__ __forceinline__ s16x8 load_cvt8(const float* __restrict__ p) {
  return pack8(*reinterpret_cast<const float4*>(p),
               *reinterpret_cast<const float4*>(p + 4));
}

#define GLL16(g, l)                                                          \
  __builtin_amdgcn_global_load_lds(                                          \
      (const __attribute__((address_space(1))) void*)(g),                    \
      (__attribute__((address_space(3))) void*)(l), 16, 0, 0)

// ---------------------------------------------------------------------------
// Kernel 1: support = x[src_idx] @ W, written DIRECTLY in MFMA-fragment-linear
// order: supTp[((kk*8 + n)*64 + lane)*8 + e] = bf16(support[kk*32 + (lane>>4)*8
// + e][n*16 + (lane&15)]).  (validated R7-R11)
// ---------------------------------------------------------------------------
__global__ __launch_bounds__(128) void support_kernel(
    const float* __restrict__ x, const float* __restrict__ W,
    const int* __restrict__ src_idx, unsigned short* __restrict__ supTp) {
  __shared__ float xrows[8][DIN];
  const int j = threadIdx.x;           // output feature 0..127
  const int s0 = blockIdx.x * 8;       // first source (k-index) of this block
#pragma unroll
  for (int i = 0; i < 8; ++i) {
    const int src = src_idx[s0 + i];
    xrows[i][j] = x[(size_t)src * DIN + j];
  }
  __syncthreads();
  float acc[8];
#pragma unroll
  for (int i = 0; i < 8; ++i) acc[i] = 0.f;
  for (int k = 0; k < DIN; ++k) {
    const float w = W[(size_t)k * DIN + j];   // coalesced across threads
#pragma unroll
    for (int i = 0; i < 8; ++i) acc[i] += xrows[i][k] * w;  // LDS broadcast
  }
  u16x8 o;
#pragma unroll
  for (int i = 0; i < 8; ++i) o[i] = f2bf(acc[i]);
  const int kk = s0 >> 5;              // 32-wide k-chunk
  const int g2 = (s0 >> 3) & 3;        // k-slot group within chunk
  const int n = j >> 4;                // n-tile
  const int lane = (j & 15) + g2 * 16; // MFMA lane holding these 8 elements
  *reinterpret_cast<u16x8*>(&supTp[(size_t)((kk * 8 + n) * 64 + lane) * 8]) = o;
}

// ---------------------------------------------------------------------------
// Kernel 2: out = LeakyReLU(A @ support) @ dense0_w^T
// R12 = R7 (best validated, 65.3us) + per-block CHUNK-OFFSET DECORRELATION:
// block b iterates chunks (i + (b&31)) & 31, so at any instant the 625 blocks
// spread their A-column windows and B-chunk reads uniformly across the whole
// address space (kills cross-block L2-slice / HBM-channel hotspotting — the
// one variable no previous round changed). Everything else identical to R7.
// Block = 128 thr / 2 waves; wave w owns rows rowBase + w*16..+15. Grid 625.
//   A: 8 gll/chunk (4 rows x 256B segs), XOR-slot-swizzled SOURCE (rule #21).
//   B: 16 gll/chunk, 1KB contiguous each (supTp fragment-linear).
// Sync: counted vmcnt(12) + raw s_barrier; never vmcnt(0) in loop.
// MFMA 16x16x32 bf16 layouts (validated R2-R11):
//   A-frag: lane l holds A[l&15][(l>>4)*8+e]; B-frag: B[(l>>4)*8+e][l&15]
//   C/D:    lane l holds C[(l>>4)*4+r][l&15]
// ---------------------------------------------------------------------------
__global__ __launch_bounds__(128) void fused_gcn_kernel(
    const float* __restrict__ A,             // [NNODES][NSRC] f32
    const unsigned short* __restrict__ supTp,// fragment-packed, 512 KB
    const float* __restrict__ Wd,            // dense0_w [DIN][DIN] f32
    float* __restrict__ out) {               // [NNODES][DIN] f32
  const int tid = threadIdx.x;
  const int lane = tid & 63;
  const int w = tid >> 6;                    // wave 0..1
  const int r16 = lane & 15;
  const int g = lane >> 4;
  const int rowBase = blockIdx.x * 32;
  const int off = blockIdx.x & 31;           // chunk-start decorrelation

  // pool: Ap [2][32 rows][64 f32] = 16 KB | Bp [2][2 kk][8 n][64 lane][8 e]
  // = 32 KB. After the K-loop (post-barrier) the first 8.7 KB are reused as
  // the per-wave act tiles.
  __shared__ __attribute__((aligned(16))) unsigned char pool[49152];
  float* Ap = (float*)pool;
  unsigned short* Bp = (unsigned short*)(pool + 16384);

  f32x4 acc[8];
#pragma unroll
  for (int n = 0; n < 8; ++n) acc[n] = (f32x4){0.f, 0.f, 0.f, 0.f};

  // ---- STAGE chunk cc (cols cc*64..+63) into buffer `buf` -----------------
  // A: instr i = w*4+i2 covers rows 4i..4i+3 (4 x 256B segments). Source col
  //    slot pre-swizzled: slot_src = (lane&15) ^ (row&7)  (involution).
  // B: instr iB = w*8+i2 -> (kk2=iB>>3, n=iB&7): 64 lanes x 16B contiguous.
#define STAGE(buf, cc)                                                        \
  {                                                                           \
    _Pragma("unroll") for (int i2 = 0; i2 < 4; ++i2) {                        \
      const int i = w * 4 + i2;                                               \
      const int row = 4 * i + (lane >> 4);                                    \
      GLL16(A + (size_t)(rowBase + row) * NSRC + (cc) * 64 +                  \
                (((lane & 15) ^ (row & 7)) << 2),                             \
            Ap + (buf) * 2048 + i * 256);                                     \
    }                                                                         \
    _Pragma("unroll") for (int i2 = 0; i2 < 8; ++i2) {                        \
      const int iB = w * 8 + i2;                                              \
      GLL16(supTp +                                                           \
                ((size_t)(((cc) * 2 + (iB >> 3)) * 8 + (iB & 7)) * 64 + lane) \
                    * 8,                                                      \
            Bp + (buf) * 8192 + iB * 512);                                    \
    }                                                                         \
  }

  // ---- COMPUTE chunk in buffer `buf` (per wave: rows w*16..+15) -----------
#define COMPUTE(buf)                                                          \
  {                                                                           \
    _Pragma("unroll") for (int kk2 = 0; kk2 < 2; ++kk2) {                     \
      const float* rb = Ap + (buf) * 2048 + (w * 16 + r16) * 64;              \
      const float4 lo = *reinterpret_cast<const float4*>(                     \
          &rb[((kk2 * 8 + g * 2) ^ (r16 & 7)) << 2]);                         \
      const float4 hi = *reinterpret_cast<const float4*>(                     \
          &rb[((kk2 * 8 + g * 2 + 1) ^ (r16 & 7)) << 2]);                     \
      const s16x8 a = pack8(lo, hi);                                          \
      _Pragma("unroll") for (int n = 0; n < 8; ++n) {                         \
        const s16x8 b = *reinterpret_cast<const s16x8*>(                      \
            &Bp[(buf) * 8192 + ((kk2 * 8 + n) * 64 + lane) * 8]);             \
        acc[n] =                                                              \
            __builtin_amdgcn_mfma_f32_16x16x32_bf16(a, b, acc[n], 0, 0, 0);   \
      }                                                                       \
    }                                                                         \
  }

  // prologue: stage first chunk of this block's permuted order
  STAGE(0, off);
  for (int c = 0; c < 31; ++c) {
    const int cnext = (c + 1 + off) & 31;
    STAGE((c & 1) ^ 1, cnext);
    asm volatile("s_waitcnt vmcnt(12)" ::: "memory");  // chunk c arrived
    __builtin_amdgcn_s_barrier();                      // all waves' staging in
    COMPUTE(c & 1);
    __builtin_amdgcn_s_barrier();                      // all reads done
  }
  asm volatile("s_waitcnt vmcnt(0)" ::: "memory");
  __builtin_amdgcn_s_barrier();
  COMPUTE(1);  // last chunk -> buffer 1

  // ---- epilogue: LeakyReLU -> act (reuse pool) -> GEMM2 -> store ----------
  __builtin_amdgcn_s_barrier();  // everyone's MFMA reads retired; pool free
  unsigned short* actw = (unsigned short*)pool + w * 2176;  // [16][136]
#pragma unroll
  for (int n = 0; n < 8; ++n)
#pragma unroll
    for (int r = 0; r < 4; ++r) {
      float v = acc[n][r];
      v = (v >= 0.f) ? v : 0.01f * v;
      actw[(g * 4 + r) * 136 + n * 16 + r16] = f2bf(v);
    }
  // own-wave write->read; compiler orders via lgkmcnt

  f32x4 acc2[8];
#pragma unroll
  for (int n = 0; n < 8; ++n) acc2[n] = (f32x4){0.f, 0.f, 0.f, 0.f};
#pragma unroll
  for (int k2 = 0; k2 < 4; ++k2) {
    const int k = k2 * 32 + g * 8;
    const s16x8 a2 = *reinterpret_cast<const s16x8*>(&actw[r16 * 136 + k]);
#pragma unroll
    for (int n = 0; n < 8; ++n) {
      const s16x8 b2 = load_cvt8(Wd + (size_t)(n * 16 + r16) * DIN + k);
      acc2[n] =
          __builtin_amdgcn_mfma_f32_16x16x32_bf16(a2, b2, acc2[n], 0, 0, 0);
    }
  }
#pragma unroll
  for (int n = 0; n < 8; ++n)
#pragma unroll
    for (int r = 0; r < 4; ++r)
      out[(size_t)(rowBase + w * 16 + g * 4 + r) * DIN + n * 16 + r16] =
          acc2[n][r];
}

// ---------------------------------------------------------------------------
extern "C" void kernel_launch(void* const* d_in, const int* in_sizes, int n_in,
                              void* d_out, int out_size, void* d_ws, size_t ws_size,
                              hipStream_t stream) {
  const float* x   = (const float*)d_in[0];   // [20000][128]
  const float* A   = (const float*)d_in[1];   // [20000][2048]
  const float* W   = (const float*)d_in[2];   // [128][128]
  const float* Wd  = (const float*)d_in[3];   // [128][128]
  const int*   src = (const int*)d_in[4];     // [2048]
  float* out = (float*)d_out;

  unsigned short* supTp = (unsigned short*)d_ws;  // 512 KB, fragment-packed

  support_kernel<<<NSRC / 8, 128, 0, stream>>>(x, W, src, supTp);
  fused_gcn_kernel<<<NNODES / 32, 128, 0, stream>>>(A, supTp, Wd, out);
}